// Round 1
// baseline (193.354 us; speedup 1.0000x reference)
//
#include <hip/hip_runtime.h>
#include <math.h>

// Shapes (fixed by reference): G=8 S=140 D=256 K=12 NEG=128 W=S-K=128 POOL=20000
#define NG 8
#define NS 140
#define ND 256
#define NK 12
#define NNEG 128
#define NW 128

// ---------------- kernel 0: zero the 24-float output ----------------
__global__ void k_zero(float* out) {
    int t = threadIdx.x;
    if (t < 24) out[t] = 0.0f;
}

// ---------------- kernel 1: locC GEMM ----------------
// C[m][n] = sum_a A[m][a]*B[n][a];  M=1024 (m=g*128+w), N=3072 (n=k*256+e), Kdim=256
// A row m -> cFeature + (g*140+w)*256 ; B row n -> W + n*256 ; C row-major (stride 3072) in ws.
#define TM 64
#define TN 64
#define TK 64
__global__ __launch_bounds__(256) void k_locC(const float* __restrict__ cF,
                                              const float* __restrict__ Wm,
                                              float* __restrict__ C) {
    __shared__ float As[TM][68];  // [m][k], stride 68 (pad: 68%32=4 keeps reads ~2-group)
    __shared__ float Bs[TN][68];  // [n][k]
    int tid = threadIdx.x;
    int m0 = blockIdx.x * TM;
    int n0 = blockIdx.y * TN;
    int tx = tid & 15, ty = tid >> 4;
    float acc[4][4] = {};
    for (int kt = 0; kt < 256; kt += TK) {
        // load 64x64 tiles, float4 along k (coalesced global reads)
        for (int p = 0; p < 4; ++p) {
            int r  = (tid >> 4) + p * 16;   // row within tile
            int kq = (tid & 15);            // float4 index within k-tile
            int m = m0 + r;
            int g = m >> 7, w = m & 127;
            float4 va = *(const float4*)(cF + (g * NS + w) * ND + kt + kq * 4);
            *(float4*)&As[r][kq * 4] = va;
            float4 vb = *(const float4*)(Wm + (n0 + r) * ND + kt + kq * 4);
            *(float4*)&Bs[r][kq * 4] = vb;
        }
        __syncthreads();
        for (int kk4 = 0; kk4 < TK / 4; ++kk4) {
            float4 a4[4], b4[4];
            for (int i = 0; i < 4; ++i) a4[i] = *(const float4*)&As[ty * 4 + i][kk4 * 4];
            for (int j = 0; j < 4; ++j) b4[j] = *(const float4*)&Bs[tx * 4 + j][kk4 * 4];
            for (int i = 0; i < 4; ++i)
                for (int j = 0; j < 4; ++j)
                    acc[i][j] += a4[i].x * b4[j].x + a4[i].y * b4[j].y +
                                 a4[i].z * b4[j].z + a4[i].w * b4[j].w;
        }
        __syncthreads();
    }
    for (int i = 0; i < 4; ++i) {
        float4 v = {acc[i][0], acc[i][1], acc[i][2], acc[i][3]};
        *(float4*)&C[(long)(m0 + ty * 4 + i) * 3072 + n0 + tx * 4] = v;
    }
}

// ---------------- kernel 2: scores + log-softmax + reduce ----------------
// One block per (g,w). 256 threads = 4 waves.
__global__ __launch_bounds__(256) void k_scores(const float* __restrict__ ws,
                                                const float* __restrict__ gtP,
                                                const float* __restrict__ other,
                                                const int* __restrict__ extIdx,
                                                float* __restrict__ out) {
    __shared__ float locS[NK][260];   // locC rows for this (g,w); stride 260 (%32==4)
    __shared__ float negS[32][260];   // one 32-row neg tile
    __shared__ float sc[NK][132];     // all 12x128 neg scores
    __shared__ float spos[NK];
    __shared__ int   idxS[NNEG];

    int bid = blockIdx.x;
    int g = bid >> 7, w = bid & 127;
    int tid = threadIdx.x;
    int wave = tid >> 6, lane = tid & 63;

    if (tid < NNEG) idxS[tid] = extIdx[(g * NNEG + tid) * NW + w];

    // load locC (12x256) as float4, coalesced
    const float* locBase = ws + (long)bid * 3072;
    for (int j = 0; j < 3; ++j) {
        int f4 = tid + 256 * j;          // 0..767 float4 index
        int k = f4 >> 6, e4 = f4 & 63;
        float4 v = *(const float4*)(locBase + f4 * 4);
        *(float4*)&locS[k][e4 * 4] = v;
    }
    __syncthreads();

    // positive scores: wave v handles k = 3v..3v+2, full-wave strided dot + shuffle reduce
    for (int c = 0; c < 3; ++c) {
        int k = wave * 3 + c;
        const float* row = gtP + (g * NS + (w + 1 + k)) * ND;
        float s = 0.f;
        for (int e = lane; e < ND; e += 64) s += locS[k][e] * row[e];
        for (int off = 32; off > 0; off >>= 1) s += __shfl_xor(s, off);
        if (lane == 0) spos[k] = s * (1.0f / 256.0f);
    }

    // negative scores, 4 tiles of 32 rows
    int k4 = wave;           // thread computes k in {k4, k4+4, k4+8}
    int n4 = lane & 7;       // covers rows n4*4 .. n4*4+3
    int rep = lane >> 3;     // 8-way e-split, interleaved (e4 = ii*8+rep)
    for (int nt = 0; nt < 4; ++nt) {
        __syncthreads();     // previous tile's compute done before overwrite
        for (int j = 0; j < 8; ++j) {
            int flat = tid + 256 * j;    // 0..2047 float4
            int i = flat >> 6, e4 = flat & 63;
            const float* row = other + (long)idxS[nt * 32 + i] * ND;
            float4 v = *(const float4*)(row + e4 * 4);
            *(float4*)&negS[i][e4 * 4] = v;
        }
        __syncthreads();
        float acc[3][4] = {};
        for (int ii = 0; ii < 8; ++ii) {
            int e4 = ii * 8 + rep;
            float4 l4[3];
            for (int c = 0; c < 3; ++c) l4[c] = *(const float4*)&locS[k4 + 4 * c][e4 * 4];
            for (int q = 0; q < 4; ++q) {
                float4 nv = *(const float4*)&negS[n4 * 4 + q][e4 * 4];
                for (int c = 0; c < 3; ++c)
                    acc[c][q] += l4[c].x * nv.x + l4[c].y * nv.y +
                                 l4[c].z * nv.z + l4[c].w * nv.w;
            }
        }
        for (int c = 0; c < 3; ++c)
            for (int q = 0; q < 4; ++q) {
                float v = acc[c][q];
                v += __shfl_xor(v, 8);
                v += __shfl_xor(v, 16);
                v += __shfl_xor(v, 32);
                if (rep == 0) sc[k4 + 4 * c][nt * 32 + n4 * 4 + q] = v * (1.0f / 256.0f);
            }
    }
    __syncthreads();

    // per-k log-softmax over [pos, 128 negs]; teams of 16 threads per k
    if (tid < NK * 16) {
        int k = tid >> 4, i = tid & 15;
        float vals[8];
        float mx = -1e30f;
        for (int j = 0; j < 8; ++j) {
            vals[j] = sc[k][i + 16 * j];
            mx = fmaxf(mx, vals[j]);
        }
        for (int off = 8; off > 0; off >>= 1) mx = fmaxf(mx, __shfl_xor(mx, off, 16));
        float negmax = mx;                 // max over negatives
        float sp = spos[k];
        float M = fmaxf(negmax, sp);
        float se = 0.f;
        for (int j = 0; j < 8; ++j) se += __expf(vals[j] - M);
        for (int off = 8; off > 0; off >>= 1) se += __shfl_xor(se, off, 16);
        if (i == 0) {
            float total = se + __expf(sp - M);
            float lp = sp - (M + __logf(total));          // logp of the positive
            atomicAdd(&out[k],      -lp * (1.0f / 1024.0f));
            atomicAdd(&out[NK + k], (sp >= negmax) ? (1.0f / 1024.0f) : 0.0f);
        }
    }
}

extern "C" void kernel_launch(void* const* d_in, const int* in_sizes, int n_in,
                              void* d_out, int out_size, void* d_ws, size_t ws_size,
                              hipStream_t stream) {
    const float* cF    = (const float*)d_in[0];   // (8,140,256)
    const float* gtP   = (const float*)d_in[1];   // (8,140,256)
    const float* other = (const float*)d_in[2];   // (20000,256)
    const int*   extIdx= (const int*)  d_in[3];   // (8,128,128)
    const float* Wm    = (const float*)d_in[4];   // (12,256,256)
    float* out = (float*)d_out;                   // 12 losses then 12 acc
    float* ws  = (float*)d_ws;                    // needs 1024*3072*4 = 12.6 MB

    k_zero<<<1, 64, 0, stream>>>(out);
    k_locC<<<dim3(16, 48), 256, 0, stream>>>(cF, Wm, ws);
    k_scores<<<1024, 256, 0, stream>>>(ws, gtP, other, extIdx, out);
}

// Round 2
// 150.801 us; speedup vs baseline: 1.2822x; 1.2822x over previous
//
#include <hip/hip_runtime.h>

// Shapes: G=8 S=140 D=256 K=12 NEG=128 W=128 POOL=20000
#define NG 8
#define NS 140
#define ND 256
#define NK 12
#define NNEG 128
#define NW 128
#define POOLN 20000

typedef __attribute__((ext_vector_type(8))) short short8;
typedef __attribute__((ext_vector_type(4))) float f32x4;

__device__ inline unsigned short f2bf(float f) {
    union { float f; unsigned u; } v; v.f = f;
    unsigned r = v.u + 0x7FFFu + ((v.u >> 16) & 1u);   // RNE
    return (unsigned short)(r >> 16);
}
__device__ inline float bf2f(unsigned short u) {
    union { unsigned u; float f; } v; v.u = ((unsigned)u) << 16;
    return v.f;
}
__device__ inline uint4 pack8(const float* p) {
    float4 x = *(const float4*)p, y = *(const float4*)(p + 4);
    uint4 u;
    u.x = f2bf(x.x) | ((unsigned)f2bf(x.y) << 16);
    u.y = f2bf(x.z) | ((unsigned)f2bf(x.w) << 16);
    u.z = f2bf(y.x) | ((unsigned)f2bf(y.y) << 16);
    u.w = f2bf(y.z) | ((unsigned)f2bf(y.w) << 16);
    return u;
}

__global__ void k_zero(float* out) {
    int t = threadIdx.x;
    if (t < 24) out[t] = 0.0f;
}

// ---------- pool fp32 -> bf16 (20000x256) ----------
__global__ __launch_bounds__(256) void k_cvt(const float* __restrict__ src,
                                             unsigned short* __restrict__ dst, int n8) {
    int t = blockIdx.x * 256 + threadIdx.x;
    if (t >= n8) return;
    uint4 u = pack8(src + t * 8);
    *(uint4*)(dst + t * 8) = u;
}

// ---------- phase 1: locC GEMM, bf16 MFMA ----------
// C[m][n] = sum_a A[m][a]*B[n][a]; M=1024 (m=g*128+w), N=3072 (n=k*256+e), Kdim=256
// 64x64 tile / block, 4 waves each 32x32, LDS tile depth 64.
#define P1PAD 72   // shorts per LDS row (64 + 8)
__global__ __launch_bounds__(256) void k_locC(const float* __restrict__ cF,
                                              const float* __restrict__ Wm,
                                              unsigned short* __restrict__ C) {
    __shared__ unsigned short As[64 * P1PAD];
    __shared__ unsigned short Bs[64 * P1PAD];
    int tid = threadIdx.x;
    int m0 = blockIdx.x * 64, n0 = blockIdx.y * 64;
    int lane = tid & 63, wv = tid >> 6;
    int wm = (wv >> 1) * 32, wn = (wv & 1) * 32;
    int lm = lane & 15, quad = lane >> 4;
    int r = tid >> 2, q = tid & 3;            // staging: row r, col-chunk q
    int g = (m0 + r) >> 7, w = (m0 + r) & 127;
    const float* aSrc = cF + (g * NS + w) * ND + q * 16;
    const float* bSrc = Wm + (n0 + r) * ND + q * 16;
    f32x4 acc[2][2] = {};
    for (int kt = 0; kt < 256; kt += 64) {
        uint4 a0 = pack8(aSrc + kt);
        uint4 a1 = pack8(aSrc + kt + 8);
        uint4 b0 = pack8(bSrc + kt);
        uint4 b1 = pack8(bSrc + kt + 8);
        if (kt) __syncthreads();
        *(uint4*)&As[r * P1PAD + q * 16] = a0;
        *(uint4*)&As[r * P1PAD + q * 16 + 8] = a1;
        *(uint4*)&Bs[r * P1PAD + q * 16] = b0;
        *(uint4*)&Bs[r * P1PAD + q * 16 + 8] = b1;
        __syncthreads();
        #pragma unroll
        for (int ks = 0; ks < 2; ++ks) {
            short8 af[2], bf[2];
            #pragma unroll
            for (int mt = 0; mt < 2; ++mt)
                af[mt] = *(const short8*)&As[(wm + mt * 16 + lm) * P1PAD + ks * 32 + quad * 8];
            #pragma unroll
            for (int nt = 0; nt < 2; ++nt)
                bf[nt] = *(const short8*)&Bs[(wn + nt * 16 + lm) * P1PAD + ks * 32 + quad * 8];
            #pragma unroll
            for (int mt = 0; mt < 2; ++mt)
                #pragma unroll
                for (int nt = 0; nt < 2; ++nt)
                    acc[mt][nt] = __builtin_amdgcn_mfma_f32_16x16x32_bf16(
                        af[mt], bf[nt], acc[mt][nt], 0, 0, 0);
        }
    }
    #pragma unroll
    for (int mt = 0; mt < 2; ++mt)
        #pragma unroll
        for (int nt = 0; nt < 2; ++nt)
            #pragma unroll
            for (int rr = 0; rr < 4; ++rr) {
                int row = m0 + wm + mt * 16 + quad * 4 + rr;
                int col = n0 + wn + nt * 16 + lm;
                C[(long)row * 3072 + col] = f2bf(acc[mt][nt][rr]);
            }
}

// ---------- phase 2: scores via MFMA + log-softmax + reduce ----------
// One block per (g,w). A = locC rows (12x256, pad to 16) in LDS;
// B = gathered neg rows, loaded straight from global as MFMA fragments.
__global__ __launch_bounds__(256) void k_scores(const unsigned short* __restrict__ locC,
                                                const float* __restrict__ gtP,
                                                const unsigned short* __restrict__ pool,
                                                const int* __restrict__ extIdx,
                                                float* __restrict__ out) {
    __shared__ unsigned short locS[16 * 264];  // row pad 264 shorts
    __shared__ float sc[NK][132];
    __shared__ float spos[NK];
    __shared__ int idxS[NNEG];

    int bid = blockIdx.x;
    int g = bid >> 7, w = bid & 127;
    int tid = threadIdx.x, lane = tid & 63, wv = tid >> 6;
    int lm = lane & 15, quad = lane >> 4;

    if (tid < NNEG) idxS[tid] = extIdx[(g * NNEG + tid) * NW + w];

    // load locC 12x256 shorts (= 384 uint4), coalesced
    const uint4* src = (const uint4*)(locC + (long)bid * 3072);
    for (int f = tid; f < 384; f += 256) {
        int k = f >> 5, e8 = f & 31;
        *(uint4*)&locS[k * 264 + e8 * 8] = src[f];
    }
    // zero pad rows 12..15 (used portion only)
    for (int f = tid; f < 128; f += 256) {
        int k = 12 + (f >> 5), e8 = f & 31;
        *(uint4*)&locS[k * 264 + e8 * 8] = make_uint4(0, 0, 0, 0);
    }
    __syncthreads();

    // positive scores: wave wv handles k = 3*wv .. 3*wv+2
    for (int c = 0; c < 3; ++c) {
        int k = wv * 3 + c;
        float4 gv = *(const float4*)(gtP + (g * NS + w + 1 + k) * ND + lane * 4);
        const unsigned short* lp = &locS[k * 264 + lane * 4];
        float s = bf2f(lp[0]) * gv.x + bf2f(lp[1]) * gv.y +
                  bf2f(lp[2]) * gv.z + bf2f(lp[3]) * gv.w;
        for (int off = 32; off; off >>= 1) s += __shfl_xor(s, off);
        if (!lane) spos[k] = s * (1.0f / 256.0f);
    }

    // negative scores: wave wv owns n-tiles {2wv, 2wv+1}
    const short8* p0 = (const short8*)(pool + (long)idxS[(wv * 2 + 0) * 16 + lm] * 256);
    const short8* p1 = (const short8*)(pool + (long)idxS[(wv * 2 + 1) * 16 + lm] * 256);
    const short8* aP = (const short8*)&locS[lm * 264 + quad * 8];
    f32x4 acc0 = {0.f, 0.f, 0.f, 0.f}, acc1 = {0.f, 0.f, 0.f, 0.f};
    #pragma unroll
    for (int ks = 0; ks < 8; ++ks) {
        short8 a = aP[ks * 4];              // locS[lm][ks*32 + quad*8 ..]
        short8 b0 = p0[ks * 4 + quad];      // neg row, 16B slice
        short8 b1 = p1[ks * 4 + quad];
        acc0 = __builtin_amdgcn_mfma_f32_16x16x32_bf16(a, b0, acc0, 0, 0, 0);
        acc1 = __builtin_amdgcn_mfma_f32_16x16x32_bf16(a, b1, acc1, 0, 0, 0);
    }
    #pragma unroll
    for (int rr = 0; rr < 4; ++rr) {
        int k = quad * 4 + rr;
        if (k < NK) {
            sc[k][(wv * 2 + 0) * 16 + lm] = acc0[rr] * (1.0f / 256.0f);
            sc[k][(wv * 2 + 1) * 16 + lm] = acc1[rr] * (1.0f / 256.0f);
        }
    }
    __syncthreads();

    // per-k log-softmax over [pos, 128 negs]; 16-thread teams per k
    if (tid < NK * 16) {
        int k = tid >> 4, i = tid & 15;
        float vals[8];
        float mx = -1e30f;
        for (int j = 0; j < 8; ++j) {
            vals[j] = sc[k][i + 16 * j];
            mx = fmaxf(mx, vals[j]);
        }
        for (int off = 8; off > 0; off >>= 1) mx = fmaxf(mx, __shfl_xor(mx, off, 16));
        float negmax = mx;
        float sp = spos[k];
        float M = fmaxf(negmax, sp);
        float se = 0.f;
        for (int j = 0; j < 8; ++j) se += __expf(vals[j] - M);
        for (int off = 8; off > 0; off >>= 1) se += __shfl_xor(se, off, 16);
        if (i == 0) {
            float total = se + __expf(sp - M);
            float lp = sp - (M + __logf(total));
            atomicAdd(&out[k],      -lp * (1.0f / 1024.0f));
            atomicAdd(&out[NK + k], (sp >= negmax) ? (1.0f / 1024.0f) : 0.0f);
        }
    }
}

extern "C" void kernel_launch(void* const* d_in, const int* in_sizes, int n_in,
                              void* d_out, int out_size, void* d_ws, size_t ws_size,
                              hipStream_t stream) {
    const float* cF     = (const float*)d_in[0];   // (8,140,256)
    const float* gtP    = (const float*)d_in[1];   // (8,140,256)
    const float* other  = (const float*)d_in[2];   // (20000,256)
    const int*   extIdx = (const int*)  d_in[3];   // (8,128,128)
    const float* Wm     = (const float*)d_in[4];   // (12,256,256)
    float* out = (float*)d_out;                    // 12 losses then 12 acc

    unsigned short* pool_bf = (unsigned short*)d_ws;                  // 20000*256 shorts = 10.24 MB
    unsigned short* locC_bf = pool_bf + (long)POOLN * ND;             // 1024*3072 shorts = 6.29 MB

    k_zero<<<1, 64, 0, stream>>>(out);
    k_cvt<<<(POOLN * ND / 8 + 255) / 256, 256, 0, stream>>>(other, pool_bf, POOLN * ND / 8);
    k_locC<<<dim3(16, 48), 256, 0, stream>>>(cF, Wm, locC_bf);
    k_scores<<<1024, 256, 0, stream>>>(locC_bf, gtP, pool_bf, extIdx, out);
}

// Round 3
// 147.025 us; speedup vs baseline: 1.3151x; 1.0257x over previous
//
#include <hip/hip_runtime.h>

// Shapes: G=8 S=140 D=256 K=12 NEG=128 W=128 POOL=20000
#define NG 8
#define NS 140
#define ND 256
#define NK 12
#define NNEG 128
#define NW 128
#define POOLN 20000

typedef __attribute__((ext_vector_type(8))) short short8;
typedef __attribute__((ext_vector_type(4))) float f32x4;

__device__ inline unsigned short f2bf(float f) {
    union { float f; unsigned u; } v; v.f = f;
    unsigned r = v.u + 0x7FFFu + ((v.u >> 16) & 1u);   // RNE
    return (unsigned short)(r >> 16);
}
__device__ inline float bf2f(unsigned short u) {
    union { unsigned u; float f; } v; v.u = ((unsigned)u) << 16;
    return v.f;
}
__device__ inline uint4 pack8(const float* p) {
    float4 x = *(const float4*)p, y = *(const float4*)(p + 4);
    uint4 u;
    u.x = f2bf(x.x) | ((unsigned)f2bf(x.y) << 16);
    u.y = f2bf(x.z) | ((unsigned)f2bf(x.w) << 16);
    u.z = f2bf(y.x) | ((unsigned)f2bf(y.y) << 16);
    u.w = f2bf(y.z) | ((unsigned)f2bf(y.w) << 16);
    return u;
}

#define P1PAD 72
#define CVT_N8 (POOLN * ND / 8)               // 640000 groups of 8
#define CVT_BLOCKS ((CVT_N8 + 255) / 256)     // 2500
#define LOC_BLOCKS 768                        // 16 x 48

// ---------- fused prep: out-zero + pool cvt + locC GEMM ----------
__global__ __launch_bounds__(256) void k_prep(const float* __restrict__ cF,
                                              const float* __restrict__ Wm,
                                              const float* __restrict__ other,
                                              unsigned short* __restrict__ pool_bf,
                                              unsigned short* __restrict__ locC_bf,
                                              float* __restrict__ out) {
    int bid = blockIdx.x;
    int tid = threadIdx.x;
    if (bid >= LOC_BLOCKS) {
        // -------- cvt branch --------
        int cb = bid - LOC_BLOCKS;
        if (cb == 0 && tid < 24) out[tid] = 0.0f;
        int t = cb * 256 + tid;
        if (t < CVT_N8) {
            uint4 u = pack8(other + t * 8);
            *(uint4*)(pool_bf + t * 8) = u;
        }
        return;
    }
    // -------- locC GEMM branch --------
    __shared__ unsigned short As[64 * P1PAD];
    __shared__ unsigned short Bs[64 * P1PAD];
    int m0 = (bid & 15) * 64, n0 = (bid >> 4) * 64;
    int lane = tid & 63, wv = tid >> 6;
    int wm = (wv >> 1) * 32, wn = (wv & 1) * 32;
    int lm = lane & 15, quad = lane >> 4;
    int r = tid >> 2, q = tid & 3;
    int g = (m0 + r) >> 7, w = (m0 + r) & 127;
    const float* aSrc = cF + (g * NS + w) * ND + q * 16;
    const float* bSrc = Wm + (n0 + r) * ND + q * 16;
    f32x4 acc[2][2] = {};
    for (int kt = 0; kt < 256; kt += 64) {
        uint4 a0 = pack8(aSrc + kt);
        uint4 a1 = pack8(aSrc + kt + 8);
        uint4 b0 = pack8(bSrc + kt);
        uint4 b1 = pack8(bSrc + kt + 8);
        if (kt) __syncthreads();
        *(uint4*)&As[r * P1PAD + q * 16] = a0;
        *(uint4*)&As[r * P1PAD + q * 16 + 8] = a1;
        *(uint4*)&Bs[r * P1PAD + q * 16] = b0;
        *(uint4*)&Bs[r * P1PAD + q * 16 + 8] = b1;
        __syncthreads();
        #pragma unroll
        for (int ks = 0; ks < 2; ++ks) {
            short8 af[2], bf[2];
            #pragma unroll
            for (int mt = 0; mt < 2; ++mt)
                af[mt] = *(const short8*)&As[(wm + mt * 16 + lm) * P1PAD + ks * 32 + quad * 8];
            #pragma unroll
            for (int nt = 0; nt < 2; ++nt)
                bf[nt] = *(const short8*)&Bs[(wn + nt * 16 + lm) * P1PAD + ks * 32 + quad * 8];
            #pragma unroll
            for (int mt = 0; mt < 2; ++mt)
                #pragma unroll
                for (int nt = 0; nt < 2; ++nt)
                    acc[mt][nt] = __builtin_amdgcn_mfma_f32_16x16x32_bf16(
                        af[mt], bf[nt], acc[mt][nt], 0, 0, 0);
        }
    }
    #pragma unroll
    for (int mt = 0; mt < 2; ++mt)
        #pragma unroll
        for (int nt = 0; nt < 2; ++nt)
            #pragma unroll
            for (int rr = 0; rr < 4; ++rr) {
                int row = m0 + wm + mt * 16 + quad * 4 + rr;
                int col = n0 + wn + nt * 16 + lm;
                locC_bf[(long)row * 3072 + col] = f2bf(acc[mt][nt][rr]);
            }
}

// ---------- scores: 512 threads (8 waves), one 16-neg tile per wave ----------
__global__ __launch_bounds__(512) void k_scores(const unsigned short* __restrict__ locC,
                                                const float* __restrict__ gtP,
                                                const unsigned short* __restrict__ pool,
                                                const int* __restrict__ extIdx,
                                                float* __restrict__ out) {
    __shared__ unsigned short locS[16 * 264];
    __shared__ float sc[NK][132];
    __shared__ float spos[NK];

    int bid = blockIdx.x;
    int g = bid >> 7, w = bid & 127;
    int tid = threadIdx.x, lane = tid & 63, wv = tid >> 6;
    int lm = lane & 15, quad = lane >> 4;

    // gather: per-lane index straight from global, then ALL 8 fragment loads up front
    int n = wv * 16 + lm;
    long rowIdx = extIdx[(g * NNEG + n) * NW + w];
    const short8* pb = (const short8*)(pool + rowIdx * 256) + quad;
    short8 b0 = pb[0],  b1 = pb[4],  b2 = pb[8],  b3 = pb[12];
    short8 b4 = pb[16], b5 = pb[20], b6 = pb[24], b7 = pb[28];

    // stage locC 12x256 (+4 zero rows) while gathers are in flight
    const uint4* src = (const uint4*)(locC + (long)bid * 3072);
    if (tid < 384) {
        int k = tid >> 5, e8 = tid & 31;
        *(uint4*)&locS[k * 264 + e8 * 8] = src[tid];
    } else {
        int f = tid - 384;
        int k = 12 + (f >> 5), e8 = f & 31;
        *(uint4*)&locS[k * 264 + e8 * 8] = make_uint4(0, 0, 0, 0);
    }
    __syncthreads();

    // positive scores: waves 0..5 handle 2 k's each
    if (wv < 6) {
        #pragma unroll
        for (int c = 0; c < 2; ++c) {
            int k = wv * 2 + c;
            float4 gv = *(const float4*)(gtP + (g * NS + w + 1 + k) * ND + lane * 4);
            const unsigned short* lp = &locS[k * 264 + lane * 4];
            float s = bf2f(lp[0]) * gv.x + bf2f(lp[1]) * gv.y +
                      bf2f(lp[2]) * gv.z + bf2f(lp[3]) * gv.w;
            for (int off = 32; off; off >>= 1) s += __shfl_xor(s, off);
            if (!lane) spos[k] = s * (1.0f / 256.0f);
        }
    }

    // neg scores: 8 MFMAs, two independent accumulator chains
    const short8* aP = (const short8*)&locS[lm * 264 + quad * 8];
    f32x4 accA = {0.f, 0.f, 0.f, 0.f}, accB = {0.f, 0.f, 0.f, 0.f};
    accA = __builtin_amdgcn_mfma_f32_16x16x32_bf16(aP[0],  b0, accA, 0, 0, 0);
    accB = __builtin_amdgcn_mfma_f32_16x16x32_bf16(aP[4],  b1, accB, 0, 0, 0);
    accA = __builtin_amdgcn_mfma_f32_16x16x32_bf16(aP[8],  b2, accA, 0, 0, 0);
    accB = __builtin_amdgcn_mfma_f32_16x16x32_bf16(aP[12], b3, accB, 0, 0, 0);
    accA = __builtin_amdgcn_mfma_f32_16x16x32_bf16(aP[16], b4, accA, 0, 0, 0);
    accB = __builtin_amdgcn_mfma_f32_16x16x32_bf16(aP[20], b5, accB, 0, 0, 0);
    accA = __builtin_amdgcn_mfma_f32_16x16x32_bf16(aP[24], b6, accA, 0, 0, 0);
    accB = __builtin_amdgcn_mfma_f32_16x16x32_bf16(aP[28], b7, accB, 0, 0, 0);
    #pragma unroll
    for (int rr = 0; rr < 4; ++rr) {
        int k = quad * 4 + rr;
        if (k < NK) sc[k][n] = (accA[rr] + accB[rr]) * (1.0f / 256.0f);
    }
    __syncthreads();

    // per-k log-softmax over [pos, 128 negs]; 16-thread teams per k (waves 0..2)
    if (tid < NK * 16) {
        int k = tid >> 4, i = tid & 15;
        float vals[8];
        float mx = -1e30f;
        for (int j = 0; j < 8; ++j) {
            vals[j] = sc[k][i + 16 * j];
            mx = fmaxf(mx, vals[j]);
        }
        for (int off = 8; off > 0; off >>= 1) mx = fmaxf(mx, __shfl_xor(mx, off, 16));
        float negmax = mx;
        float sp = spos[k];
        float M = fmaxf(negmax, sp);
        float se = 0.f;
        for (int j = 0; j < 8; ++j) se += __expf(vals[j] - M);
        for (int off = 8; off > 0; off >>= 1) se += __shfl_xor(se, off, 16);
        if (i == 0) {
            float total = se + __expf(sp - M);
            float lp = sp - (M + __logf(total));
            atomicAdd(&out[k],      -lp * (1.0f / 1024.0f));
            atomicAdd(&out[NK + k], (sp >= negmax) ? (1.0f / 1024.0f) : 0.0f);
        }
    }
}

extern "C" void kernel_launch(void* const* d_in, const int* in_sizes, int n_in,
                              void* d_out, int out_size, void* d_ws, size_t ws_size,
                              hipStream_t stream) {
    const float* cF     = (const float*)d_in[0];   // (8,140,256)
    const float* gtP    = (const float*)d_in[1];   // (8,140,256)
    const float* other  = (const float*)d_in[2];   // (20000,256)
    const int*   extIdx = (const int*)  d_in[3];   // (8,128,128)
    const float* Wm     = (const float*)d_in[4];   // (12,256,256)
    float* out = (float*)d_out;                    // 12 losses then 12 acc

    unsigned short* pool_bf = (unsigned short*)d_ws;       // 20000*256 shorts
    unsigned short* locC_bf = pool_bf + (long)POOLN * ND;  // 1024*3072 shorts

    k_prep<<<LOC_BLOCKS + CVT_BLOCKS, 256, 0, stream>>>(cF, Wm, other, pool_bf, locC_bf, out);
    k_scores<<<1024, 512, 0, stream>>>(locC_bf, gtP, pool_bf, extIdx, out);
}

// Round 4
// 99.731 us; speedup vs baseline: 1.9388x; 1.4742x over previous
//
#include <hip/hip_runtime.h>

// Shapes: G=8 S=140 D=256 K=12 NEG=128 W=128 POOL=20000
#define NG 8
#define NS 140
#define ND 256
#define NK 12
#define NNEG 128
#define NW 128
#define POOLN 20000

typedef __attribute__((ext_vector_type(8))) short short8;
typedef __attribute__((ext_vector_type(4))) float f32x4;

__device__ inline unsigned short f2bf(float f) {
    union { float f; unsigned u; } v; v.f = f;
    unsigned r = v.u + 0x7FFFu + ((v.u >> 16) & 1u);   // RNE
    return (unsigned short)(r >> 16);
}
__device__ inline float bf2f(unsigned short u) {
    union { unsigned u; float f; } v; v.u = ((unsigned)u) << 16;
    return v.f;
}
__device__ inline uint4 pack8(const float* p) {
    float4 x = *(const float4*)p, y = *(const float4*)(p + 4);
    uint4 u;
    u.x = f2bf(x.x) | ((unsigned)f2bf(x.y) << 16);
    u.y = f2bf(x.z) | ((unsigned)f2bf(x.w) << 16);
    u.z = f2bf(y.x) | ((unsigned)f2bf(y.y) << 16);
    u.w = f2bf(y.z) | ((unsigned)f2bf(y.w) << 16);
    return u;
}

#define P1PAD 72
#define CVT_N8 (POOLN * ND / 8)               // 640000 groups of 8
#define CVT_BLOCKS ((CVT_N8 + 255) / 256)     // 2500
#define LOC_BLOCKS 768                        // 16 x 48
#define TR_BLOCKS 512                         // extIdx transpose: 131072 elems

// ---------- fused prep: pool cvt + locC GEMM + extIdx transpose ----------
__global__ __launch_bounds__(256) void k_prep(const float* __restrict__ cF,
                                              const float* __restrict__ Wm,
                                              const float* __restrict__ other,
                                              const int* __restrict__ extIdx,
                                              unsigned short* __restrict__ pool_bf,
                                              unsigned short* __restrict__ locC_bf,
                                              int* __restrict__ extIdxT) {
    int bid = blockIdx.x;
    int tid = threadIdx.x;
    if (bid >= LOC_BLOCKS + CVT_BLOCKS) {
        // -------- extIdx transpose: extIdxT[(g*128+w)*128+n] = extIdx[(g*128+n)*128+w]
        int t = (bid - LOC_BLOCKS - CVT_BLOCKS) * 256 + tid;   // 0..131071
        int gw = t >> 7, n = t & 127;
        int g = gw >> 7, w = gw & 127;
        extIdxT[t] = extIdx[(g * NNEG + n) * NW + w];
        return;
    }
    if (bid >= LOC_BLOCKS) {
        // -------- cvt branch --------
        int t = (bid - LOC_BLOCKS) * 256 + tid;
        if (t < CVT_N8) {
            uint4 u = pack8(other + t * 8);
            *(uint4*)(pool_bf + t * 8) = u;
        }
        return;
    }
    // -------- locC GEMM branch --------
    __shared__ unsigned short As[64 * P1PAD];
    __shared__ unsigned short Bs[64 * P1PAD];
    int m0 = (bid & 15) * 64, n0 = (bid >> 4) * 64;
    int lane = tid & 63, wv = tid >> 6;
    int wm = (wv >> 1) * 32, wn = (wv & 1) * 32;
    int lm = lane & 15, quad = lane >> 4;
    int r = tid >> 2, q = tid & 3;
    int g = (m0 + r) >> 7, w = (m0 + r) & 127;
    const float* aSrc = cF + (g * NS + w) * ND + q * 16;
    const float* bSrc = Wm + (n0 + r) * ND + q * 16;
    f32x4 acc[2][2] = {};
    for (int kt = 0; kt < 256; kt += 64) {
        uint4 a0 = pack8(aSrc + kt);
        uint4 a1 = pack8(aSrc + kt + 8);
        uint4 b0 = pack8(bSrc + kt);
        uint4 b1 = pack8(bSrc + kt + 8);
        if (kt) __syncthreads();
        *(uint4*)&As[r * P1PAD + q * 16] = a0;
        *(uint4*)&As[r * P1PAD + q * 16 + 8] = a1;
        *(uint4*)&Bs[r * P1PAD + q * 16] = b0;
        *(uint4*)&Bs[r * P1PAD + q * 16 + 8] = b1;
        __syncthreads();
        #pragma unroll
        for (int ks = 0; ks < 2; ++ks) {
            short8 af[2], bf[2];
            #pragma unroll
            for (int mt = 0; mt < 2; ++mt)
                af[mt] = *(const short8*)&As[(wm + mt * 16 + lm) * P1PAD + ks * 32 + quad * 8];
            #pragma unroll
            for (int nt = 0; nt < 2; ++nt)
                bf[nt] = *(const short8*)&Bs[(wn + nt * 16 + lm) * P1PAD + ks * 32 + quad * 8];
            #pragma unroll
            for (int mt = 0; mt < 2; ++mt)
                #pragma unroll
                for (int nt = 0; nt < 2; ++nt)
                    acc[mt][nt] = __builtin_amdgcn_mfma_f32_16x16x32_bf16(
                        af[mt], bf[nt], acc[mt][nt], 0, 0, 0);
        }
    }
    #pragma unroll
    for (int mt = 0; mt < 2; ++mt)
        #pragma unroll
        for (int nt = 0; nt < 2; ++nt)
            #pragma unroll
            for (int rr = 0; rr < 4; ++rr) {
                int row = m0 + wm + mt * 16 + quad * 4 + rr;
                int col = n0 + wn + nt * 16 + lm;
                locC_bf[(long)row * 3072 + col] = f2bf(acc[mt][nt][rr]);
            }
}

// ---------- scores: 512 threads (8 waves), one 16-neg tile per wave ----------
// NO atomics: per-block partials stored to ws, reduced by k_reduce.
__global__ __launch_bounds__(512) void k_scores(const unsigned short* __restrict__ locC,
                                                const float* __restrict__ gtP,
                                                const unsigned short* __restrict__ pool,
                                                const int* __restrict__ extIdxT,
                                                float* __restrict__ partial) {
    __shared__ unsigned short locS[16 * 264];
    __shared__ float sc[NK][132];
    __shared__ float spos[NK];

    int bid = blockIdx.x;
    int g = bid >> 7, w = bid & 127;
    int tid = threadIdx.x, lane = tid & 63, wv = tid >> 6;
    int lm = lane & 15, quad = lane >> 4;

    // gather index: coalesced (one line per wave), then all 8 fragment loads
    int n = wv * 16 + lm;
    long rowIdx = (long)extIdxT[bid * NNEG + n];
    const short8* pb = (const short8*)(pool + rowIdx * 256) + quad;
    short8 b0 = pb[0],  b1 = pb[4],  b2 = pb[8],  b3 = pb[12];
    short8 b4 = pb[16], b5 = pb[20], b6 = pb[24], b7 = pb[28];

    // stage locC 12x256 (+4 zero rows) while gathers are in flight
    const uint4* src = (const uint4*)(locC + (long)bid * 3072);
    if (tid < 384) {
        int k = tid >> 5, e8 = tid & 31;
        *(uint4*)&locS[k * 264 + e8 * 8] = src[tid];
    } else {
        int f = tid - 384;
        int k = 12 + (f >> 5), e8 = f & 31;
        *(uint4*)&locS[k * 264 + e8 * 8] = make_uint4(0, 0, 0, 0);
    }
    __syncthreads();

    // positive scores: waves 0..5 handle 2 k's each
    if (wv < 6) {
        #pragma unroll
        for (int c = 0; c < 2; ++c) {
            int k = wv * 2 + c;
            float4 gv = *(const float4*)(gtP + (g * NS + w + 1 + k) * ND + lane * 4);
            const unsigned short* lp = &locS[k * 264 + lane * 4];
            float s = bf2f(lp[0]) * gv.x + bf2f(lp[1]) * gv.y +
                      bf2f(lp[2]) * gv.z + bf2f(lp[3]) * gv.w;
            for (int off = 32; off; off >>= 1) s += __shfl_xor(s, off);
            if (!lane) spos[k] = s * (1.0f / 256.0f);
        }
    }

    // neg scores: 8 MFMAs, two independent accumulator chains
    const short8* aP = (const short8*)&locS[lm * 264 + quad * 8];
    f32x4 accA = {0.f, 0.f, 0.f, 0.f}, accB = {0.f, 0.f, 0.f, 0.f};
    accA = __builtin_amdgcn_mfma_f32_16x16x32_bf16(aP[0],  b0, accA, 0, 0, 0);
    accB = __builtin_amdgcn_mfma_f32_16x16x32_bf16(aP[4],  b1, accB, 0, 0, 0);
    accA = __builtin_amdgcn_mfma_f32_16x16x32_bf16(aP[8],  b2, accA, 0, 0, 0);
    accB = __builtin_amdgcn_mfma_f32_16x16x32_bf16(aP[12], b3, accB, 0, 0, 0);
    accA = __builtin_amdgcn_mfma_f32_16x16x32_bf16(aP[16], b4, accA, 0, 0, 0);
    accB = __builtin_amdgcn_mfma_f32_16x16x32_bf16(aP[20], b5, accB, 0, 0, 0);
    accA = __builtin_amdgcn_mfma_f32_16x16x32_bf16(aP[24], b6, accA, 0, 0, 0);
    accB = __builtin_amdgcn_mfma_f32_16x16x32_bf16(aP[28], b7, accB, 0, 0, 0);
    #pragma unroll
    for (int rr = 0; rr < 4; ++rr) {
        int k = quad * 4 + rr;
        if (k < NK) sc[k][n] = (accA[rr] + accB[rr]) * (1.0f / 256.0f);
    }
    __syncthreads();

    // per-k log-softmax over [pos, 128 negs]; 16-thread teams per k
    if (tid < NK * 16) {
        int k = tid >> 4, i = tid & 15;
        float vals[8];
        float mx = -1e30f;
        for (int j = 0; j < 8; ++j) {
            vals[j] = sc[k][i + 16 * j];
            mx = fmaxf(mx, vals[j]);
        }
        for (int off = 8; off > 0; off >>= 1) mx = fmaxf(mx, __shfl_xor(mx, off, 16));
        float negmax = mx;
        float sp = spos[k];
        float M = fmaxf(negmax, sp);
        float se = 0.f;
        for (int j = 0; j < 8; ++j) se += __expf(vals[j] - M);
        for (int off = 8; off > 0; off >>= 1) se += __shfl_xor(se, off, 16);
        if (i == 0) {
            float total = se + __expf(sp - M);
            float lp = sp - (M + __logf(total));
            partial[k * 1024 + bid]        = -lp;                         // loss partial
            partial[(NK + k) * 1024 + bid] = (sp >= negmax) ? 1.0f : 0.0f; // acc partial
        }
    }
}

// ---------- final reduce: 24 outputs, sum 1024 partials each ----------
__global__ __launch_bounds__(256) void k_reduce(const float* __restrict__ partial,
                                                float* __restrict__ out) {
    int j = blockIdx.x;                 // 0..23
    int tid = threadIdx.x;
    const float* p = partial + j * 1024;
    float s = p[tid] + p[tid + 256] + p[tid + 512] + p[tid + 768];
    for (int off = 32; off; off >>= 1) s += __shfl_xor(s, off);
    __shared__ float wsum[4];
    if ((tid & 63) == 0) wsum[tid >> 6] = s;
    __syncthreads();
    if (tid == 0) out[j] = (wsum[0] + wsum[1] + wsum[2] + wsum[3]) * (1.0f / 1024.0f);
}

extern "C" void kernel_launch(void* const* d_in, const int* in_sizes, int n_in,
                              void* d_out, int out_size, void* d_ws, size_t ws_size,
                              hipStream_t stream) {
    const float* cF     = (const float*)d_in[0];   // (8,140,256)
    const float* gtP    = (const float*)d_in[1];   // (8,140,256)
    const float* other  = (const float*)d_in[2];   // (20000,256)
    const int*   extIdx = (const int*)  d_in[3];   // (8,128,128)
    const float* Wm     = (const float*)d_in[4];   // (12,256,256)
    float* out = (float*)d_out;                    // 12 losses then 12 acc

    unsigned short* pool_bf = (unsigned short*)d_ws;       // 20000*256 shorts = 10.24 MB
    unsigned short* locC_bf = pool_bf + (long)POOLN * ND;  // 1024*3072 shorts = 6.29 MB
    int* extIdxT = (int*)(locC_bf + (long)1024 * 3072);    // 131072 ints = 512 KB
    float* partial = (float*)(extIdxT + 131072);           // 24*1024 floats = 96 KB

    k_prep<<<LOC_BLOCKS + CVT_BLOCKS + TR_BLOCKS, 256, 0, stream>>>(
        cF, Wm, other, extIdx, pool_bf, locC_bf, extIdxT);
    k_scores<<<1024, 512, 0, stream>>>(locC_bf, gtP, pool_bf, extIdxT, partial);
    k_reduce<<<24, 256, 0, stream>>>(partial, out);
}